// Round 30
// baseline (81.830 us; speedup 1.0000x reference)
//
#include <hip/hip_runtime.h>
#include <math.h>

#define BATCH 64
#define HH 256
#define WW 256
#define HW 65536            // 256*256 pixels per image
#define NPIX (BATCH * HW)   // 4194304
#define NBINS 50
#define SENT_P 0x7FFFFFFF   // background marker

#define TW 64
#define TH 64
#define TN (TW * TH)
#define TILES_X (WW / TW)   // 4
#define TILES_PER_IMG 16
#define LIST_STRIDE 32768   // max tile-roots per image

__device__ __forceinline__ int aload(const int* p) {
    return __hip_atomic_load(p, __ATOMIC_RELAXED, __HIP_MEMORY_SCOPE_AGENT);
}
__device__ __forceinline__ void astore(int* p, int v) {
    __hip_atomic_store(p, v, __ATOMIC_RELAXED, __HIP_MEMORY_SCOPE_AGENT);
}

__device__ __forceinline__ int runstart64(unsigned long long m, int c) {
    unsigned long long sh = (~m) << (63 - c);
    return sh ? (c - __clzll(sh) + 1) : 0;
}
__device__ __forceinline__ int runlen64(unsigned long long m, int c) {
    unsigned long long sh = ~(m >> c);
    return sh ? (__ffsll(sh) - 1) : 64;
}
// wave argmax: max val, tie -> min idx (== np first-occurrence)
__device__ __forceinline__ void wave_argmax(int& bv, int& bi) {
#pragma unroll
    for (int off = 32; off > 0; off >>= 1) {
        int ov = __shfl_xor(bv, off);
        int oi = __shfl_xor(bi, off);
        if (ov > bv || (ov == bv && oi < bi)) { bv = ov; bi = oi; }
    }
}

// ---- K1: histogram partials (8 blocks/image) + zero per-image root counter ----
__global__ void k_hist(const float* __restrict__ att, int* __restrict__ histp,
                       int* __restrict__ rootcnt) {
    __shared__ int h[NBINS];
    const int b = blockIdx.y, c = blockIdx.x, t = threadIdx.x;
    if (c == 0 && t == 0) rootcnt[b] = 0;       // published at kernel boundary
    if (t < NBINS) h[t] = 0;
    __syncthreads();
    const float4* src = (const float4*)(att + (size_t)b * HW) + c * 2048;
    for (int i = t; i < 2048; i += 256) {
        float4 v = src[i];
        atomicAdd(&h[min((int)(v.x * 50.0f), 49)], 1);
        atomicAdd(&h[min((int)(v.y * 50.0f), 49)], 1);
        atomicAdd(&h[min((int)(v.z * 50.0f), 49)], 1);
        atomicAdd(&h[min((int)(v.w * 50.0f), 49)], 1);
    }
    __syncthreads();
    if (t < NBINS) histp[(b * 8 + c) * 64 + t] = h[t];
}

// ---- LDS union-find over run-start nodes ----
__device__ __forceinline__ void lunite(int* lp, int a, int b) {
    int x = a, p = lp[x];
    while (p != x) { int gp = lp[p]; if (gp != p) lp[x] = gp; x = gp; p = lp[x]; }
    int ra = x;
    x = b; p = lp[x];
    while (p != x) { int gp = lp[p]; if (gp != p) lp[x] = gp; x = gp; p = lp[x]; }
    int rb = x;
    while (ra != rb) {
        int lo = min(ra, rb), hi = max(ra, rb);
        int old = atomicMin(&lp[hi], lo);
        if (old == hi) return;
        x = lo; p = lp[x];
        while (p != x) { int gp = lp[p]; if (gp != p) lp[x] = gp; x = gp; p = lp[x]; }
        ra = x;
        x = old; p = lp[x];
        while (p != x) { int gp = lp[p]; if (gp != p) lp[x] = gp; x = gp; p = lp[x]; }
        rb = x;
    }
}
// masked find (after length deposits: root slots carry size in high bits)
__device__ __forceinline__ int lfindm(int* lp, int x) {
    while (true) {
        int p = lp[x] & 0xFFFF;
        if (p == x) return x;
        int gp = lp[p] & 0xFFFF;
        if (gp != p) lp[x] = gp;
        x = gp;
    }
}

// ---- K2: fused threshold + run-based tile CC (1024 threads) ----
// R30 change: each thread's float4 of att is PREFETCHED into registers at
// kernel entry — the load has no dependence on the threshold, so its ~200-900
// cycle latency hides under Phase 0's histp reads + wave argmax instead of
// sitting on the post-threshold critical path (the layout-invariant residue).
__global__ __launch_bounds__(1024)
void k_init_cc(const float* __restrict__ att, const int* __restrict__ histp,
               int* parent, int* __restrict__ cnt, int* __restrict__ list,
               int* __restrict__ rootcnt) {
    __shared__ int lp[TN];
    __shared__ unsigned long long msk[TH];
    __shared__ int s_nroots, s_base;
    const int tile = blockIdx.x;
    const int b = blockIdx.y;
    const int t = threadIdx.x;
    const int wv = t >> 6, ln = t & 63;          // 16 waves
    const int tr0 = (tile / TILES_X) * TH;
    const int tc0 = (tile % TILES_X) * TW;
    const float* A = att + (size_t)b * HW;

    // Prefetch: thread t owns px-quad (r = t>>4, c4 = (t&15)*4) — issue NOW.
    const int pr = t >> 4, pc4 = (t & 15) * 4;
    float4 pv4 = *(const float4*)(A + (tr0 + pr) * WW + tc0 + pc4);

    // Phase 0: per-wave inline threshold (R11-proven f64 semantics)
    int h_ln = 0;
    if (ln < NBINS)
        for (int c = 0; c < 8; ++c) h_ln += histp[(b * 8 + c) * 64 + ln];
    int bv = (ln < NBINS) ? h_ln : -1, bi = ln;
    wave_argmax(bv, bi);
    const int ind_max = bi;
    int bv2 = (ln < NBINS && ln > ind_max) ? h_ln : -1, bi2 = ln;
    wave_argmax(bv2, bi2);
    const double tv = (double)bi2 / 50.0;

    // Phase 1: per-quad fg nibble from registers -> row masks via wave ops.
    // Thread t covers cols pc4..pc4+3 of row pr; lanes 0..15 of each wave hold
    // one full row (16 quads). Ballot trick: each lane contributes 4 bits at
    // position (lane&15)*4 via two ballots (even/odd bit pairs) — instead use
    // simple LDS atomicOr (proven R20 path) but from registers (no load stall).
    if (t < TH) msk[t] = 0ull;
    if (t == 0) s_nroots = 0;
    __syncthreads();
    {
        unsigned long long nib =
              (((double)pv4.x > tv) ? 1ull : 0ull)
            | (((double)pv4.y > tv) ? 2ull : 0ull)
            | (((double)pv4.z > tv) ? 4ull : 0ull)
            | (((double)pv4.w > tv) ? 8ull : 0ull);
        if (nib)
            atomicOr((unsigned long long*)&msk[pr], nib << pc4);
    }
    __syncthreads();

    // Phase 1b: init lp at run starts (4 rows per wave, from complete masks)
#pragma unroll
    for (int k = 0; k < 4; ++k) {
        int r = wv + 16 * k;
        unsigned long long m = msk[r];
        if (((m >> ln) & 1ull) && (ln == 0 || !((m >> (ln - 1)) & 1ull)))
            lp[r * TW + ln] = r * TW + ln;
    }
    __syncthreads();

    // Phase 2: vertical unions, one per overlap segment
#pragma unroll
    for (int k = 0; k < 4; ++k) {
        int r = wv + 16 * k;
        if (r >= TH - 1) continue;
        unsigned long long m0 = msk[r], m1 = msk[r + 1];
        unsigned long long ov = m0 & m1;
        if (((ov >> ln) & 1ull) && (ln == 0 || !((ov >> (ln - 1)) & 1ull)))
            lunite(lp, r * TW + runstart64(m0, ln),
                       (r + 1) * TW + runstart64(m1, ln));
    }
    __syncthreads();

    // Phase 3: deposit run lengths at local roots
#pragma unroll
    for (int k = 0; k < 4; ++k) {
        int r = wv + 16 * k;
        unsigned long long m = msk[r];
        if (((m >> ln) & 1ull) && (ln == 0 || !((m >> (ln - 1)) & 1ull))) {
            int L = runlen64(m, ln);
            int root = lfindm(lp, r * TW + ln);
            atomicAdd(&lp[root], L << 16);
        }
    }
    __syncthreads();

    // Phase 4a: write PURE parent (own px-quad); roots take LDS ranks,
    //           cached in two scalar slots (no dynamic register indexing)
    int* P = parent + (size_t)b * HW;
    int g0 = -1, z0 = 0, k0 = 0;
    int g1 = -1, z1 = 0, k1 = 0;
    {
        unsigned long long m = msk[pr];
        int w[4];
#pragma unroll
        for (int j = 0; j < 4; ++j) {
            int c = pc4 + j, l = pr * TW + c;
            if (!((m >> c) & 1ull)) { w[j] = SENT_P; continue; }
            int node = pr * TW + runstart64(m, c);
            int root = lfindm(lp, node);
            int groot = (tr0 + (root >> 6)) * WW + tc0 + (root & (TW - 1));
            w[j] = groot;                              // PURE (root -> self)
            if (l == root) {                           // <= 2 roots per thread
                int size = lp[root] >> 16;             // 1..4096
                cnt[(size_t)b * HW + groot] = 0;       // zero-init (plain)
                int rank = atomicAdd(&s_nroots, 1);    // LDS atomic (block-local)
                if (g0 < 0) { g0 = groot; z0 = size; k0 = rank; }
                else        { g1 = groot; z1 = size; k1 = rank; }
            }
        }
        *(int4*)(P + (tr0 + pr) * WW + tc0 + pc4) = make_int4(w[0], w[1], w[2], w[3]);
    }
    __syncthreads();
    if (t == 0) s_base = atomicAdd(&rootcnt[b], s_nroots);   // 16 RMWs/image total
    __syncthreads();

    // Phase 4b: write cached roots into claimed list range
    {
        int base = b * LIST_STRIDE + s_base;
        if (g0 >= 0) list[base + k0] = g0 | ((z0 - 1) << 16);
        if (g1 >= 0) list[base + k1] = g1 | ((z1 - 1) << 16);
    }
}

// ---- K3: boundary merge — PURE atomicMin linking (R14-proven) ----
__device__ __forceinline__ int findroot_h(int* P, int x) {
    int p = aload(P + x);
    while (p != x) {
        int gp = aload(P + p);
        astore(P + x, gp);
        x = gp; p = aload(P + x);
    }
    return x;
}
__device__ __forceinline__ void unite(int* P, int a, int b) {
    int ra = findroot_h(P, a);
    int rb = findroot_h(P, b);
    while (ra != rb) {
        int lo = min(ra, rb), hi = max(ra, rb);
        int old = atomicMin(&P[hi], lo);
        if (old == hi) return;
        ra = findroot_h(P, lo);
        rb = findroot_h(P, old);
    }
}
__global__ void k_bmerge(int* parent) {
    int g = blockIdx.x * blockDim.x + threadIdx.x;
    if (g >= BATCH * 1536) return;
    int b = g / 1536, e = g % 1536;
    int* P = parent + (size_t)b * HW;
    int l, m;
    if (e < 768) {          // vertical edges: cols {63,127,191}
        int k = e / 256, row = e & 255;
        l = row * WW + (TW - 1 + TW * k); m = l + 1;
    } else {                // horizontal edges: rows {63,127,191}
        int e2 = e - 768;
        int k = e2 / 256, col = e2 & 255;
        l = (TH - 1 + TH * k) * WW + col; m = l + WW;
    }
    if (aload(P + l) != SENT_P && aload(P + m) != SENT_P) unite(P, l, m);
}

// ---- K4: accumulate — one thread per tile root: walk frozen parent, one add ----
__global__ void k_acc(const int* __restrict__ parent, int* __restrict__ cnt,
                      const int* __restrict__ list, const int* __restrict__ rootcnt) {
    int g = blockIdx.x * blockDim.x + threadIdx.x;
    int b = g / LIST_STRIDE, i = g - b * LIST_STRIDE;
    if (b >= BATCH || i >= rootcnt[b]) return;
    int e = list[b * LIST_STRIDE + i];
    int x = e & 0xFFFF;
    int size = (e >> 16) + 1;
    const int* P = parent + (size_t)b * HW;
    int p = P[x];                              // plain loads: topology frozen
    while (p != x) { x = p; p = P[x]; }
    atomicAdd(&cnt[(size_t)b * HW + x], size); // fire-and-forget, memory-side
}

// ---- K5: finalize — plain L1-hot walk + cnt lookup; hw exp2/log2 pow ----
__global__ void k_final(const float* __restrict__ att, const int* __restrict__ parent,
                        const int* __restrict__ cnt, float* __restrict__ out) {
    int g = blockIdx.x * blockDim.x + threadIdx.x;
    int base = g * 4;
    if (base >= NPIX) return;
    const int* P = parent + (base & ~(HW - 1));
    const int* C = cnt + (base & ~(HW - 1));
    float4 v = ((const float4*)att)[g];
    int4 pv = ((const int4*)parent)[g];
    int vv[4] = {pv.x, pv.y, pv.z, pv.w};
    float xs[4] = {v.x, v.y, v.z, v.w};
    float ys[4];
#pragma unroll
    for (int j = 0; j < 4; ++j) {
        float x = xs[j];
        int w = vv[j];
        if (w == SENT_P) { ys[j] = x; continue; }
        int xi = w, p = P[xi];
        while (p != xi) { xi = p; p = P[xi]; }     // depth ~1-2 post-halving
        int a = C[xi];
        if (a <= 1) { ys[j] = x; continue; }       // x^1 == x
        float e = 1.0f / sqrtf((float)a);
        // x > thr >= 0 here; v_log_f32/v_exp_f32: |err| ~ |log2 x|*ulp << 2e-2
        ys[j] = __builtin_amdgcn_exp2f(e * __builtin_amdgcn_logf(x));
    }
    ((float4*)out)[g] = make_float4(ys[0], ys[1], ys[2], ys[3]);
}

// ================= fallback (tiny ws): R11-proven monolith =================
__global__ __launch_bounds__(1024)
void k_all(const float* __restrict__ att, float* out) {
    const int b = blockIdx.x;
    const int t = threadIdx.x;
    const float* A = att + (size_t)b * HW;
    int* L = (int*)out + (size_t)b * HW;
    __shared__ int hist[NBINS];
    __shared__ double s_thr;
    __shared__ int s_changed;
    for (int i = t; i < NBINS; i += 1024) hist[i] = 0;
    if (t == 0) s_changed = 0;
    __syncthreads();
    const float4* src4 = (const float4*)A;
    for (int i = t; i < HW / 4; i += 1024) {
        float4 v = src4[i];
        atomicAdd(&hist[min((int)(v.x * 50.0f), 49)], 1);
        atomicAdd(&hist[min((int)(v.y * 50.0f), 49)], 1);
        atomicAdd(&hist[min((int)(v.z * 50.0f), 49)], 1);
        atomicAdd(&hist[min((int)(v.w * 50.0f), 49)], 1);
    }
    __syncthreads();
    if (t == 0) {
        int ind_max = 0, bv = hist[0];
        for (int j = 1; j < NBINS; ++j)
            if (hist[j] > bv) { bv = hist[j]; ind_max = j; }
        int ind_sec = 0, bv2 = -1;
        for (int j = 1; j < NBINS; ++j) {
            int v = (j > ind_max) ? hist[j] : -1;
            if (v > bv2) { bv2 = v; ind_sec = j; }
        }
        s_thr = (double)ind_sec / 50.0;
    }
    __syncthreads();
    const double tv = s_thr;
    for (int i = t; i < HW / 4; i += 1024) {
        float4 v = src4[i];
        int l = i * 4;
        astore(L + l + 0, ((double)v.x > tv) ? (l + 0) : SENT_P);
        astore(L + l + 1, ((double)v.y > tv) ? (l + 1) : SENT_P);
        astore(L + l + 2, ((double)v.z > tv) ? (l + 2) : SENT_P);
        astore(L + l + 3, ((double)v.w > tv) ? (l + 3) : SENT_P);
    }
    __syncthreads();
    for (;;) {
        int changed = 0;
        for (int p = t; p < HW; p += 1024) {
            int v = aload(L + p);
            if (v == SENT_P) continue;
            int m = v;
            int col = p & (WW - 1), row = p >> 8;
            if (col > 0)      m = min(m, aload(L + p - 1));
            if (col < WW - 1) m = min(m, aload(L + p + 1));
            if (row > 0)      m = min(m, aload(L + p - WW));
            if (row < HH - 1) m = min(m, aload(L + p + WW));
            m = min(m, aload(L + m));
            if (m < v) { astore(L + p, m); changed = 1; }
        }
        if (changed) s_changed = 1;
        __syncthreads();
        int ch = s_changed;
        __syncthreads();
        if (!ch) break;
        if (t == 0) s_changed = 0;
        __syncthreads();
    }
    for (int p = t; p < HW; p += 1024) {
        int v = aload(L + p);
        if (v == SENT_P) continue;
        int lo = v & 0xFFFF;
        if (lo != p) atomicAdd((unsigned int*)(L + lo), 0x10000u);
    }
    __syncthreads();
    for (int p = t; p < HW; p += 1024) {
        int v = aload(L + p);
        if (v == SENT_P) continue;
        int lo = v & 0xFFFF;
        if (lo != p) astore(L + p, aload(L + lo));
    }
    __syncthreads();
    for (int p = t; p < HW; p += 1024) {
        float x = A[p];
        unsigned v = (unsigned)aload(L + p);
        float y = x;
        if (v != (unsigned)SENT_P) {
            float a = (float)((v >> 16) + 1u);
            y = powf(x, 1.0f / sqrtf(a));
        }
        out[(size_t)b * HW + p] = y;
    }
}

extern "C" void kernel_launch(void* const* d_in, const int* in_sizes, int n_in,
                              void* d_out, int out_size, void* d_ws, size_t ws_size,
                              hipStream_t stream) {
    const float* att = (const float*)d_in[0];
    float* out = (float*)d_out;
    (void)in_sizes; (void)n_in; (void)out_size;

    const size_t PAR_B  = (size_t)NPIX * 4;                 // 16 MB
    const size_t CNT_B  = (size_t)NPIX * 4;                 // 16 MB
    const size_t LIST_B = (size_t)BATCH * LIST_STRIDE * 4;  // 8 MB
    const size_t HIST_B = (size_t)BATCH * 8 * 64 * 4;       // 128 KB
    if (ws_size < PAR_B + CNT_B + LIST_B + HIST_B + 1024) {
        k_all<<<BATCH, 1024, 0, stream>>>(att, out);        // proven fallback
        return;
    }
    int* parent  = (int*)d_ws;
    int* cnt     = (int*)((char*)d_ws + PAR_B);
    int* list    = (int*)((char*)d_ws + PAR_B + CNT_B);
    int* histp   = (int*)((char*)d_ws + PAR_B + CNT_B + LIST_B);
    int* rootcnt = (int*)((char*)d_ws + PAR_B + CNT_B + LIST_B + HIST_B);

    k_hist<<<dim3(8, BATCH), 256, 0, stream>>>(att, histp, rootcnt);
    k_init_cc<<<dim3(TILES_PER_IMG, BATCH), 1024, 0, stream>>>(att, histp, parent,
                                                               cnt, list, rootcnt);
    k_bmerge<<<(BATCH * 1536 + 255) / 256, 256, 0, stream>>>(parent);
    k_acc<<<(BATCH * LIST_STRIDE) / 256, 256, 0, stream>>>(parent, cnt, list, rootcnt);
    k_final<<<NPIX / (256 * 4), 256, 0, stream>>>(att, parent, cnt, out);
}